// Round 1
// baseline (724.333 us; speedup 1.0000x reference)
//
#include <hip/hip_runtime.h>
#include <stdint.h>

#define BB 16
#define CC 4
#define HH 768
#define WW 768
#define HW (HH * WW)          // 589824
#define NPIX (BB * HW)        // 9437184
#define NIMG (BB * (CC - 1))  // 48

typedef unsigned long long ull;

// ---------------- union-find helpers ----------------

__device__ __forceinline__ int find_root(int* P, int i) {
    int p = P[i];
    while (p != i) {
        int gp = P[p];
        P[i] = gp;   // path halving (benign race: writes only ancestors)
        i = p;
        p = gp;
    }
    return i;
}

__device__ __forceinline__ void merge(int* P, int a, int b) {
    a = find_root(P, a);
    b = find_root(P, b);
    while (a != b) {
        if (a < b) { int t = a; a = b; b = t; }  // a = larger root
        int old = atomicCAS(&P[a], a, b);        // attach larger under smaller
        if (old == a) return;
        a = find_root(P, old);
        b = find_root(P, b);
    }
}

// ---------------- kernels ----------------

// argmax over 4 channels; init labels, parent, counts(=0), best(=0)
__global__ void k_argmax_init(const float* __restrict__ pred,
                              uint8_t* __restrict__ labels,
                              int* __restrict__ parent,
                              uint32_t* __restrict__ counts,
                              ull* __restrict__ best) {
    int t = blockIdx.x * blockDim.x + threadIdx.x;
    if (t < NIMG) best[t] = 0ull;
    if (t >= NPIX) return;
    int b = t / HW;
    int i = t - b * HW;
    const float* p = pred + (size_t)b * CC * HW + i;
    float v0 = p[0];
    float v1 = p[HW];
    float v2 = p[2 * HW];
    float v3 = p[3 * HW];
    int lab = 0;
    float bv = v0;
    if (v1 > bv) { bv = v1; lab = 1; }
    if (v2 > bv) { bv = v2; lab = 2; }
    if (v3 > bv) { bv = v3; lab = 3; }
    labels[t] = (uint8_t)lab;
    parent[t] = lab ? t : -1;
    counts[t] = 0u;
}

// union right & down neighbors with equal nonzero label (within same image)
__global__ void k_merge(const uint8_t* __restrict__ labels, int* parent) {
    int t = blockIdx.x * blockDim.x + threadIdx.x;
    if (t >= NPIX) return;
    uint8_t lab = labels[t];
    if (!lab) return;
    int i = t % HW;
    int w = i % WW;
    if (w + 1 < WW && labels[t + 1] == lab) merge(parent, t, t + 1);
    if (i + WW < HW && labels[t + WW] == lab) merge(parent, t, t + WW);
}

// flatten each pixel to its root
__global__ void k_flatten(const uint8_t* __restrict__ labels, int* parent) {
    int t = blockIdx.x * blockDim.x + threadIdx.x;
    if (t >= NPIX) return;
    if (!labels[t]) return;
    int p = parent[t];
    while (parent[p] != p) p = parent[p];
    parent[t] = p;
}

// component sizes keyed by root pixel index
__global__ void k_count(const uint8_t* __restrict__ labels,
                        const int* __restrict__ parent,
                        uint32_t* __restrict__ counts) {
    int t = blockIdx.x * blockDim.x + threadIdx.x;
    if (t >= NPIX) return;
    if (!labels[t]) return;
    atomicAdd(&counts[parent[t]], 1u);
}

// per (batch, class): max over roots of key = (count<<32) | ~root
// max count, tie -> smallest root (matches jnp.argmax first-occurrence)
__global__ void k_best(const uint8_t* __restrict__ labels,
                       const uint32_t* __restrict__ counts,
                       ull* __restrict__ best) {
    __shared__ ull sbest[3];
    if (threadIdx.x < 3) sbest[threadIdx.x] = 0ull;
    __syncthreads();
    int t = blockIdx.x * blockDim.x + threadIdx.x;
    if (t < NPIX) {
        uint32_t cnt = counts[t];
        if (cnt) {
            int c = (int)labels[t] - 1;  // root pixel carries its class
            ull key = ((ull)cnt << 32) | (ull)(~(uint32_t)t);
            atomicMax(&sbest[c], key);
        }
    }
    __syncthreads();
    if (threadIdx.x < 3 && sbest[threadIdx.x]) {
        int b = (int)(((long long)blockIdx.x * blockDim.x) / HW);  // block within one image
        atomicMax(&best[b * 3 + threadIdx.x], sbest[threadIdx.x]);
    }
}

// final output: ch0 = 1 - any-largest-comp, ch c = (lab==c && in largest comp of c)
__global__ void k_output(const uint8_t* __restrict__ labels,
                         const int* __restrict__ parent,
                         const ull* __restrict__ best,
                         float* __restrict__ out) {
    int t = blockIdx.x * blockDim.x + threadIdx.x;
    if (t >= NPIX) return;
    int b = t / HW;
    int i = t - b * HW;
    uint8_t lab = labels[t];
    float fg = 0.0f;
    if (lab) {
        ull bk = best[b * 3 + (int)lab - 1];
        uint32_t cnt = (uint32_t)(bk >> 32);
        int root = (int)(~(uint32_t)bk);
        if (cnt && parent[t] == root) fg = 1.0f;
    }
    float* o = out + (size_t)b * CC * HW + i;
    o[0] = 1.0f - fg;
    o[HW] = (lab == 1) ? fg : 0.0f;
    o[2 * HW] = (lab == 2) ? fg : 0.0f;
    o[3 * HW] = (lab == 3) ? fg : 0.0f;
}

// ---------------- launch ----------------

extern "C" void kernel_launch(void* const* d_in, const int* in_sizes, int n_in,
                              void* d_out, int out_size, void* d_ws, size_t ws_size,
                              hipStream_t stream) {
    const float* pred = (const float*)d_in[0];
    float* out = (float*)d_out;

    // workspace layout
    uint8_t* labels = (uint8_t*)d_ws;                       // NPIX bytes
    int* parent = (int*)((char*)d_ws + NPIX);               // NPIX * 4 bytes
    ull* best = (ull*)((char*)d_ws + NPIX + (size_t)NPIX * 4);  // NIMG * 8 bytes
    // counts reuse d_out's first NPIX uint32 (overwritten by k_output later)
    uint32_t* counts = (uint32_t*)d_out;

    const int TPB = 256;
    const int NB = (NPIX + TPB - 1) / TPB;  // 36864

    k_argmax_init<<<NB, TPB, 0, stream>>>(pred, labels, parent, counts, best);
    k_merge<<<NB, TPB, 0, stream>>>(labels, parent);
    k_flatten<<<NB, TPB, 0, stream>>>(labels, parent);
    k_count<<<NB, TPB, 0, stream>>>(labels, parent, counts);
    k_best<<<NB, TPB, 0, stream>>>(labels, counts, best);
    k_output<<<NB, TPB, 0, stream>>>(labels, parent, best, out);
}

// Round 2
// 454.153 us; speedup vs baseline: 1.5949x; 1.5949x over previous
//
#include <hip/hip_runtime.h>
#include <stdint.h>

#define BB 16
#define CC 4
#define HH 768
#define WW 768
#define HW (HH * WW)          // 589824
#define NPIX (BB * HW)        // 9437184
#define NIMG (BB * (CC - 1))  // 48
#define BEST_STRIDE 16        // ull entries -> 128 B per (img,class): no line sharing

typedef unsigned long long ull;

// ---------------- union-find helpers ----------------

__device__ __forceinline__ int find_root(int* P, int i) {
    int p = P[i];
    while (p != i) {
        int gp = P[p];
        P[i] = gp;   // path halving (benign race: writes only ancestors)
        i = p;
        p = gp;
    }
    return i;
}

__device__ __forceinline__ void merge(int* P, int a, int b) {
    a = find_root(P, a);
    b = find_root(P, b);
    while (a != b) {
        if (a < b) { int t = a; a = b; b = t; }  // a = larger root
        int old = atomicCAS(&P[a], a, b);        // attach larger under smaller
        if (old == a) return;
        a = find_root(P, old);
        b = find_root(P, b);
    }
}

__device__ __forceinline__ ull umax64(ull a, ull b) { return a > b ? a : b; }

// ---------------- kernels ----------------

// argmax over 4 channels; init labels, parent, counts(=0), best(=0)
__global__ void k_argmax_init(const float* __restrict__ pred,
                              uint8_t* __restrict__ labels,
                              int* __restrict__ parent,
                              uint32_t* __restrict__ counts,
                              ull* __restrict__ best) {
    int t = blockIdx.x * blockDim.x + threadIdx.x;
    if (t < NIMG * BEST_STRIDE) best[t] = 0ull;
    if (t >= NPIX) return;
    int b = t / HW;
    int i = t - b * HW;
    const float* p = pred + (size_t)b * CC * HW + i;
    float v0 = p[0];
    float v1 = p[HW];
    float v2 = p[2 * HW];
    float v3 = p[3 * HW];
    int lab = 0;
    float bv = v0;
    if (v1 > bv) { bv = v1; lab = 1; }
    if (v2 > bv) { bv = v2; lab = 2; }
    if (v3 > bv) { bv = v3; lab = 3; }
    labels[t] = (uint8_t)lab;
    parent[t] = lab ? t : -1;
    counts[t] = 0u;
}

// union right & down neighbors with equal nonzero label (within same image)
__global__ void k_merge(const uint8_t* __restrict__ labels, int* parent) {
    int t = blockIdx.x * blockDim.x + threadIdx.x;
    if (t >= NPIX) return;
    uint8_t lab = labels[t];
    if (!lab) return;
    int i = t % HW;
    int w = i % WW;
    if (w + 1 < WW && labels[t + 1] == lab) merge(parent, t, t + 1);
    if (i + WW < HW && labels[t + WW] == lab) merge(parent, t, t + WW);
}

// flatten each pixel to its root AND count component sizes (root in register)
__global__ void k_flatten_count(const uint8_t* __restrict__ labels,
                                int* __restrict__ parent,
                                uint32_t* __restrict__ counts) {
    int t = blockIdx.x * blockDim.x + threadIdx.x;
    if (t >= NPIX) return;
    if (!labels[t]) return;
    int p = parent[t];
    while (parent[p] != p) p = parent[p];
    parent[t] = p;
    atomicAdd(&counts[p], 1u);
}

// per (img, class) max over roots of key = (count<<32) | ~root_index
// hierarchical: regs -> wave shuffle -> LDS (no atomics) -> 3 global atomics/block
#define BEST_BLK_PER_IMG 128
#define BEST_TPB 256
#define BEST_PIX_PER_BLK (HW / BEST_BLK_PER_IMG)  // 4608
__global__ void k_best(const uint8_t* __restrict__ labels,
                       const uint32_t* __restrict__ counts,
                       ull* __restrict__ best) {
    __shared__ ull sw[(BEST_TPB / 64) * 3];
    int img = blockIdx.x / BEST_BLK_PER_IMG;
    int chunk = blockIdx.x % BEST_BLK_PER_IMG;
    int base = img * HW + chunk * BEST_PIX_PER_BLK;

    ull l0 = 0, l1 = 0, l2 = 0;
    for (int k = 0; k < BEST_PIX_PER_BLK; k += BEST_TPB) {
        int t = base + k + (int)threadIdx.x;
        uint32_t cnt = counts[t];
        if (cnt) {
            int c = (int)labels[t] - 1;  // root pixel carries its class
            ull key = ((ull)cnt << 32) | (ull)(~(uint32_t)t);
            if (c == 0) l0 = umax64(l0, key);
            else if (c == 1) l1 = umax64(l1, key);
            else l2 = umax64(l2, key);
        }
    }
    // 64-lane butterfly per class
    #pragma unroll
    for (int m = 1; m < 64; m <<= 1) {
        l0 = umax64(l0, __shfl_xor(l0, m, 64));
        l1 = umax64(l1, __shfl_xor(l1, m, 64));
        l2 = umax64(l2, __shfl_xor(l2, m, 64));
    }
    int lane = threadIdx.x & 63;
    int wid = threadIdx.x >> 6;
    if (lane == 0) { sw[wid * 3 + 0] = l0; sw[wid * 3 + 1] = l1; sw[wid * 3 + 2] = l2; }
    __syncthreads();
    if (threadIdx.x < 3) {
        ull m = 0;
        for (int w = 0; w < BEST_TPB / 64; ++w) m = umax64(m, sw[w * 3 + threadIdx.x]);
        if (m) atomicMax(&best[(img * 3 + (int)threadIdx.x) * BEST_STRIDE], m);
    }
}

// final output: ch0 = 1 - any-largest-comp, ch c = (lab==c && in largest comp of c)
__global__ void k_output(const uint8_t* __restrict__ labels,
                         const int* __restrict__ parent,
                         const ull* __restrict__ best,
                         float* __restrict__ out) {
    int t = blockIdx.x * blockDim.x + threadIdx.x;
    if (t >= NPIX) return;
    int b = t / HW;
    int i = t - b * HW;
    uint8_t lab = labels[t];
    float fg = 0.0f;
    if (lab) {
        ull bk = best[(b * 3 + (int)lab - 1) * BEST_STRIDE];
        uint32_t cnt = (uint32_t)(bk >> 32);
        int root = (int)(~(uint32_t)bk);
        if (cnt && parent[t] == root) fg = 1.0f;
    }
    float* o = out + (size_t)b * CC * HW + i;
    o[0] = 1.0f - fg;
    o[HW] = (lab == 1) ? fg : 0.0f;
    o[2 * HW] = (lab == 2) ? fg : 0.0f;
    o[3 * HW] = (lab == 3) ? fg : 0.0f;
}

// ---------------- launch ----------------

extern "C" void kernel_launch(void* const* d_in, const int* in_sizes, int n_in,
                              void* d_out, int out_size, void* d_ws, size_t ws_size,
                              hipStream_t stream) {
    const float* pred = (const float*)d_in[0];
    float* out = (float*)d_out;

    // workspace layout
    uint8_t* labels = (uint8_t*)d_ws;                            // NPIX bytes
    int* parent = (int*)((char*)d_ws + NPIX);                    // NPIX*4 bytes
    ull* best = (ull*)((char*)d_ws + NPIX + (size_t)NPIX * 4);   // NIMG*BEST_STRIDE*8 bytes
    // counts reuse d_out's first NPIX uint32 (overwritten by k_output later)
    uint32_t* counts = (uint32_t*)d_out;

    const int TPB = 256;
    const int NB = (NPIX + TPB - 1) / TPB;  // 36864

    k_argmax_init<<<NB, TPB, 0, stream>>>(pred, labels, parent, counts, best);
    k_merge<<<NB, TPB, 0, stream>>>(labels, parent);
    k_flatten_count<<<NB, TPB, 0, stream>>>(labels, parent, counts);
    k_best<<<BB * BEST_BLK_PER_IMG, BEST_TPB, 0, stream>>>(labels, counts, best);
    k_output<<<NB, TPB, 0, stream>>>(labels, parent, best, out);
}

// Round 3
// 295.600 us; speedup vs baseline: 2.4504x; 1.5364x over previous
//
#include <hip/hip_runtime.h>
#include <stdint.h>

#define BB 16
#define CC 4
#define HH 768
#define WW 768
#define HW (HH * WW)          // 589824
#define NPIX (BB * HW)        // 9437184
#define NIMG (BB * (CC - 1))  // 48
#define BEST_STRIDE 16        // ull entries -> 128 B per (img,class)

#define TS 64                 // tile side
#define TPI (WW / TS)         // 12 tiles per image dim
#define TILES_PER_IMG (TPI * TPI)  // 144
#define TPIX (TS * TS)        // 4096
#define CCL_TPB 256

typedef unsigned long long ull;

// ---------------- global union-find ----------------

__device__ __forceinline__ int find_root(int* P, int i) {
    int p = P[i];
    while (p != i) {
        int gp = P[p];
        P[i] = gp;   // path halving (benign race)
        i = p;
        p = gp;
    }
    return i;
}

__device__ __forceinline__ void merge(int* P, int a, int b) {
    a = find_root(P, a);
    b = find_root(P, b);
    while (a != b) {
        if (a < b) { int t = a; a = b; b = t; }  // a = larger root
        int old = atomicCAS(&P[a], a, b);        // attach larger under smaller
        if (old == a) return;
        a = find_root(P, old);
        b = find_root(P, b);
    }
}

// ---------------- LDS union-find ----------------

__device__ __forceinline__ int lfind(int* P, int i) {
    int p = P[i];
    while (p != i) {
        int gp = P[p];
        P[i] = gp;
        i = p;
        p = gp;
    }
    return i;
}

__device__ __forceinline__ void lmerge(int* P, int a, int b) {
    a = lfind(P, a);
    b = lfind(P, b);
    while (a != b) {
        if (a < b) { int t = a; a = b; b = t; }
        int old = atomicCAS(&P[a], a, b);
        if (old == a) return;
        a = lfind(P, old);
        b = lfind(P, b);
    }
}

__device__ __forceinline__ ull umax64(ull a, ull b) { return a > b ? a : b; }

// ---------------- kernels ----------------

// per 64x64 tile: argmax over 4 channels -> labels; full local CCL in LDS;
// write parent = global index of tile-local root (-1 for background); zero counts
__global__ __launch_bounds__(CCL_TPB) void k_tile_ccl(
        const float* __restrict__ pred,
        uint8_t* __restrict__ labels,
        int* __restrict__ parent,
        uint32_t* __restrict__ counts,
        ull* __restrict__ best) {
    __shared__ int sp[TPIX];
    __shared__ uint8_t slab[TPIX];

    if (blockIdx.x == 0) {
        for (int i = threadIdx.x; i < NIMG * BEST_STRIDE; i += CCL_TPB) best[i] = 0ull;
    }

    int img = blockIdx.x / TILES_PER_IMG;
    int tile = blockIdx.x % TILES_PER_IMG;
    int tr = (tile / TPI) * TS;
    int tc = (tile % TPI) * TS;
    const float* pb = pred + (size_t)img * CC * HW;

    // phase 1: argmax + init
    for (int k = 0; k < TPIX; k += CCL_TPB) {
        int li = k + (int)threadIdx.x;
        int r = li >> 6, c = li & 63;
        int gi = (tr + r) * WW + tc + c;
        float v0 = pb[gi];
        float v1 = pb[gi + HW];
        float v2 = pb[gi + 2 * HW];
        float v3 = pb[gi + 3 * HW];
        int lab = 0;
        float bv = v0;
        if (v1 > bv) { bv = v1; lab = 1; }
        if (v2 > bv) { bv = v2; lab = 2; }
        if (v3 > bv) { bv = v3; lab = 3; }
        slab[li] = (uint8_t)lab;
        sp[li] = lab ? li : -1;
        labels[img * HW + gi] = (uint8_t)lab;
        counts[img * HW + gi] = 0u;
    }
    __syncthreads();

    // phase 2: local merges (internal tile edges only)
    for (int k = 0; k < TPIX; k += CCL_TPB) {
        int li = k + (int)threadIdx.x;
        uint8_t lab = slab[li];
        if (!lab) continue;
        int c = li & 63;
        if (c + 1 < TS && slab[li + 1] == lab) lmerge(sp, li, li + 1);
        if (li + TS < TPIX && slab[li + TS] == lab) lmerge(sp, li, li + TS);
    }
    __syncthreads();

    // phase 3: flatten to local root, write global parent
    for (int k = 0; k < TPIX; k += CCL_TPB) {
        int li = k + (int)threadIdx.x;
        int r = li >> 6, c = li & 63;
        int gidx = img * HW + (tr + r) * WW + tc + c;
        int pv = -1;
        if (slab[li]) {
            int p = li;
            while (sp[p] != p) p = sp[p];
            pv = img * HW + (tr + (p >> 6)) * WW + tc + (p & 63);
        }
        parent[gidx] = pv;
    }
}

// merge across tile borders only (right edge of each tile col, bottom edge of each tile row)
#define VEDGES ((TPI - 1) * HH)          // 8448
#define EDGES_PER_IMG (2 * (TPI - 1) * HH)  // 16896
__global__ void k_border_merge(const uint8_t* __restrict__ labels, int* parent) {
    int t = blockIdx.x * blockDim.x + threadIdx.x;
    if (t >= BB * EDGES_PER_IMG) return;
    int img = t / EDGES_PER_IMG;
    int e = t % EDGES_PER_IMG;
    int a, b;
    if (e < VEDGES) {
        int j = e / HH, r = e % HH;
        int c = j * TS + TS - 1;
        a = r * WW + c;
        b = a + 1;
    } else {
        e -= VEDGES;
        int j = e / WW, c = e % WW;
        int r = j * TS + TS - 1;
        a = r * WW + c;
        b = a + WW;
    }
    int ga = img * HW + a, gb = img * HW + b;
    uint8_t la = labels[ga];
    if (la && labels[gb] == la) merge(parent, ga, gb);
}

// flatten each pixel to its global root and count component sizes
__global__ void k_flatten_count(int* __restrict__ parent, uint32_t* __restrict__ counts) {
    int t = blockIdx.x * blockDim.x + threadIdx.x;
    if (t >= NPIX) return;
    int p = parent[t];
    if (p < 0) return;
    while (true) {
        int pp = parent[p];
        if (pp == p) break;
        p = pp;
    }
    parent[t] = p;
    atomicAdd(&counts[p], 1u);
}

// per (img, class) max over roots of key = (count<<32) | ~root_index
#define BEST_BLK_PER_IMG 144
#define BEST_TPB 256
#define BEST_PIX_PER_BLK (HW / BEST_BLK_PER_IMG)  // 4096
__global__ void k_best(const uint8_t* __restrict__ labels,
                       const uint32_t* __restrict__ counts,
                       ull* __restrict__ best) {
    __shared__ ull sw[(BEST_TPB / 64) * 3];
    int img = blockIdx.x / BEST_BLK_PER_IMG;
    int chunk = blockIdx.x % BEST_BLK_PER_IMG;
    int base = img * HW + chunk * BEST_PIX_PER_BLK;

    ull l0 = 0, l1 = 0, l2 = 0;
    for (int k = 0; k < BEST_PIX_PER_BLK; k += BEST_TPB * 4) {
        int t = base + k + (int)threadIdx.x * 4;
        uint4 cv = *(const uint4*)&counts[t];
        if (cv.x | cv.y | cv.z | cv.w) {
            uchar4 lv = *(const uchar4*)&labels[t];
            uint32_t cs[4] = {cv.x, cv.y, cv.z, cv.w};
            uint8_t ls[4] = {lv.x, lv.y, lv.z, lv.w};
            #pragma unroll
            for (int j = 0; j < 4; ++j) {
                if (cs[j]) {
                    int c = (int)ls[j] - 1;
                    ull key = ((ull)cs[j] << 32) | (ull)(~(uint32_t)(t + j));
                    if (c == 0) l0 = umax64(l0, key);
                    else if (c == 1) l1 = umax64(l1, key);
                    else l2 = umax64(l2, key);
                }
            }
        }
    }
    #pragma unroll
    for (int m = 1; m < 64; m <<= 1) {
        l0 = umax64(l0, __shfl_xor(l0, m, 64));
        l1 = umax64(l1, __shfl_xor(l1, m, 64));
        l2 = umax64(l2, __shfl_xor(l2, m, 64));
    }
    int lane = threadIdx.x & 63;
    int wid = threadIdx.x >> 6;
    if (lane == 0) { sw[wid * 3 + 0] = l0; sw[wid * 3 + 1] = l1; sw[wid * 3 + 2] = l2; }
    __syncthreads();
    if (threadIdx.x < 3) {
        ull m = 0;
        for (int w = 0; w < BEST_TPB / 64; ++w) m = umax64(m, sw[w * 3 + threadIdx.x]);
        if (m) atomicMax(&best[(img * 3 + (int)threadIdx.x) * BEST_STRIDE], m);
    }
}

// final output, 4 pixels per thread, float4 stores per channel
__global__ void k_output(const uint8_t* __restrict__ labels,
                         const int* __restrict__ parent,
                         const ull* __restrict__ best,
                         float* __restrict__ out) {
    int q = blockIdx.x * blockDim.x + threadIdx.x;
    if (q >= NPIX / 4) return;
    int t = q * 4;
    int b = t / HW;
    int i = t - b * HW;
    uchar4 lv = *(const uchar4*)&labels[t];
    int4 pv = *(const int4*)&parent[t];
    // roots of the largest component per class; empty class -> ~0 = -1, never matches
    int root[3];
    root[0] = (int)(~(uint32_t)best[(b * 3 + 0) * BEST_STRIDE]);
    root[1] = (int)(~(uint32_t)best[(b * 3 + 1) * BEST_STRIDE]);
    root[2] = (int)(~(uint32_t)best[(b * 3 + 2) * BEST_STRIDE]);

    uint8_t ls[4] = {lv.x, lv.y, lv.z, lv.w};
    int ps[4] = {pv.x, pv.y, pv.z, pv.w};
    float fg[4];
    #pragma unroll
    for (int j = 0; j < 4; ++j)
        fg[j] = (ls[j] && ps[j] == root[ls[j] - 1]) ? 1.0f : 0.0f;

    float4 o0, o1, o2, o3;
    float* c0 = &o0.x; float* c1 = &o1.x; float* c2 = &o2.x; float* c3 = &o3.x;
    #pragma unroll
    for (int j = 0; j < 4; ++j) {
        c0[j] = 1.0f - fg[j];
        c1[j] = (ls[j] == 1) ? fg[j] : 0.0f;
        c2[j] = (ls[j] == 2) ? fg[j] : 0.0f;
        c3[j] = (ls[j] == 3) ? fg[j] : 0.0f;
    }
    float* o = out + (size_t)b * CC * HW + i;
    *(float4*)&o[0] = o0;
    *(float4*)&o[HW] = o1;
    *(float4*)&o[2 * HW] = o2;
    *(float4*)&o[3 * HW] = o3;
}

// ---------------- launch ----------------

extern "C" void kernel_launch(void* const* d_in, const int* in_sizes, int n_in,
                              void* d_out, int out_size, void* d_ws, size_t ws_size,
                              hipStream_t stream) {
    const float* pred = (const float*)d_in[0];
    float* out = (float*)d_out;

    uint8_t* labels = (uint8_t*)d_ws;                            // NPIX bytes
    int* parent = (int*)((char*)d_ws + NPIX);                    // NPIX*4 bytes
    ull* best = (ull*)((char*)d_ws + NPIX + (size_t)NPIX * 4);   // NIMG*BEST_STRIDE*8
    uint32_t* counts = (uint32_t*)d_out;  // reuse d_out; overwritten by k_output

    const int TPB = 256;

    k_tile_ccl<<<BB * TILES_PER_IMG, CCL_TPB, 0, stream>>>(pred, labels, parent, counts, best);
    k_border_merge<<<(BB * EDGES_PER_IMG + TPB - 1) / TPB, TPB, 0, stream>>>(labels, parent);
    k_flatten_count<<<(NPIX + TPB - 1) / TPB, TPB, 0, stream>>>(parent, counts);
    k_best<<<BB * BEST_BLK_PER_IMG, BEST_TPB, 0, stream>>>(labels, counts, best);
    k_output<<<(NPIX / 4 + TPB - 1) / TPB, TPB, 0, stream>>>(labels, parent, best, out);
}

// Round 4
// 185.601 us; speedup vs baseline: 3.9026x; 1.5927x over previous
//
#include <hip/hip_runtime.h>
#include <stdint.h>

#define BB 16
#define CC 4
#define HH 768
#define WW 768
#define HW (HH * WW)          // 589824
#define NPIX (BB * HW)        // 9437184
#define NIMG (BB * (CC - 1))  // 48
#define BEST_STRIDE 16        // ull entries -> 128 B per (img,class)

#define TS 64                 // tile side
#define TPI (WW / TS)         // 12 tiles per image dim
#define TILES_PER_IMG (TPI * TPI)  // 144
#define TPIX (TS * TS)        // 4096
#define CCL_TPB 256

typedef unsigned long long ull;

// ---------------- global union-find (border merges only) ----------------

__device__ __forceinline__ int find_root(int* P, int i) {
    int p = P[i];
    while (p != i) {
        int gp = P[p];
        P[i] = gp;   // path halving (benign race)
        i = p;
        p = gp;
    }
    return i;
}

__device__ __forceinline__ void merge(int* P, int a, int b) {
    a = find_root(P, a);
    b = find_root(P, b);
    while (a != b) {
        if (a < b) { int t = a; a = b; b = t; }  // a = larger root
        int old = atomicCAS(&P[a], a, b);        // attach larger under smaller
        if (old == a) return;
        a = find_root(P, old);
        b = find_root(P, b);
    }
}

// ---------------- LDS union-find ----------------

__device__ __forceinline__ int lfind(int* P, int i) {
    int p = P[i];
    while (p != i) {
        int gp = P[p];
        P[i] = gp;
        i = p;
        p = gp;
    }
    return i;
}

__device__ __forceinline__ void lmerge(int* P, int a, int b) {
    a = lfind(P, a);
    b = lfind(P, b);
    while (a != b) {
        if (a < b) { int t = a; a = b; b = t; }
        int old = atomicCAS(&P[a], a, b);
        if (old == a) return;
        a = lfind(P, old);
        b = lfind(P, b);
    }
}

__device__ __forceinline__ ull umax64(ull a, ull b) { return a > b ? a : b; }

// ---------------- kernels ----------------

// per 64x64 tile: argmax -> labels; local CCL in LDS; local component counts in LDS.
// writes: labels; parent[pix] = global idx of tile-local root (-1 bg);
//         counts[pix] = local component size at local-root pixels, 0 elsewhere.
__global__ __launch_bounds__(CCL_TPB) void k_tile_ccl(
        const float* __restrict__ pred,
        uint8_t* __restrict__ labels,
        int* __restrict__ parent,
        uint32_t* __restrict__ counts,
        ull* __restrict__ best) {
    __shared__ int sp[TPIX];
    __shared__ uint8_t slab[TPIX];
    __shared__ int scount[TPIX];

    if (blockIdx.x == 0) {
        for (int i = threadIdx.x; i < NIMG * BEST_STRIDE; i += CCL_TPB) best[i] = 0ull;
    }

    int img = blockIdx.x / TILES_PER_IMG;
    int tile = blockIdx.x % TILES_PER_IMG;
    int tr = (tile / TPI) * TS;
    int tc = (tile % TPI) * TS;
    const float* pb = pred + (size_t)img * CC * HW;

    // phase 1: argmax + init, 4 px/thread
    for (int k = 0; k < TPIX; k += CCL_TPB * 4) {
        int li = k + (int)threadIdx.x * 4;
        int r = li >> 6, c = li & 63;
        int gi = (tr + r) * WW + tc + c;
        float4 v0 = *(const float4*)&pb[gi];
        float4 v1 = *(const float4*)&pb[gi + HW];
        float4 v2 = *(const float4*)&pb[gi + 2 * HW];
        float4 v3 = *(const float4*)&pb[gi + 3 * HW];
        const float* a0 = &v0.x; const float* a1 = &v1.x;
        const float* a2 = &v2.x; const float* a3 = &v3.x;
        uchar4 lout;
        uint8_t* lj = &lout.x;
        #pragma unroll
        for (int j = 0; j < 4; ++j) {
            int lab = 0;
            float bv = a0[j];
            if (a1[j] > bv) { bv = a1[j]; lab = 1; }
            if (a2[j] > bv) { bv = a2[j]; lab = 2; }
            if (a3[j] > bv) { bv = a3[j]; lab = 3; }
            slab[li + j] = (uint8_t)lab;
            sp[li + j] = lab ? li + j : -1;
            scount[li + j] = 0;
            lj[j] = (uint8_t)lab;
        }
        *(uchar4*)&labels[img * HW + gi] = lout;
    }
    __syncthreads();

    // phase 2: local merges (internal tile edges)
    for (int k = 0; k < TPIX; k += CCL_TPB) {
        int li = k + (int)threadIdx.x;
        uint8_t lab = slab[li];
        if (!lab) continue;
        int c = li & 63;
        if (c + 1 < TS && slab[li + 1] == lab) lmerge(sp, li, li + 1);
        if (li + TS < TPIX && slab[li + TS] == lab) lmerge(sp, li, li + TS);
    }
    __syncthreads();

    // phase 3a: compress to local root + LDS count
    for (int k = 0; k < TPIX; k += CCL_TPB) {
        int li = k + (int)threadIdx.x;
        if (slab[li]) {
            int p = sp[li];
            while (true) { int pp = sp[p]; if (pp == p) break; p = pp; }
            sp[li] = p;
            atomicAdd(&scount[p], 1);
        }
    }
    __syncthreads();

    // phase 3b: write parent & counts, 4 px/thread
    for (int k = 0; k < TPIX; k += CCL_TPB * 4) {
        int li = k + (int)threadIdx.x * 4;
        int r = li >> 6, c = li & 63;
        int gbase = img * HW + (tr + r) * WW + tc + c;
        int4 pout; uint4 cout;
        int* pj = &pout.x; uint32_t* cj = &cout.x;
        #pragma unroll
        for (int j = 0; j < 4; ++j) {
            int p = sp[li + j];
            pj[j] = (p < 0) ? -1 : img * HW + (tr + (p >> 6)) * WW + tc + (p & 63);
            cj[j] = (p == li + j) ? (uint32_t)scount[li + j] : 0u;
        }
        *(int4*)&parent[gbase] = pout;
        *(uint4*)&counts[gbase] = cout;
    }
}

// merge across tile borders only
#define VEDGES ((TPI - 1) * HH)             // 8448
#define EDGES_PER_IMG (2 * (TPI - 1) * HH)  // 16896
__global__ void k_border_merge(const uint8_t* __restrict__ labels, int* parent) {
    int t = blockIdx.x * blockDim.x + threadIdx.x;
    if (t >= BB * EDGES_PER_IMG) return;
    int img = t / EDGES_PER_IMG;
    int e = t % EDGES_PER_IMG;
    int a, b;
    if (e < VEDGES) {
        int j = e / HH, r = e % HH;
        int c = j * TS + TS - 1;
        a = r * WW + c;
        b = a + 1;
    } else {
        e -= VEDGES;
        int j = e / WW, c = e % WW;
        int r = j * TS + TS - 1;
        a = r * WW + c;
        b = a + WW;
    }
    int ga = img * HW + a, gb = img * HW + b;
    uint8_t la = labels[ga];
    if (la && labels[gb] == la) merge(parent, ga, gb);
}

// for each local root (counts>0): chase to global root, point parent directly at it,
// move its local count to the global root (atomic only for merged roots ~50k total)
__global__ void k_compress(int* __restrict__ parent, uint32_t* __restrict__ counts) {
    int t = blockIdx.x * blockDim.x + threadIdx.x;
    if (t >= NPIX) return;
    uint32_t cnt = counts[t];
    if (!cnt) return;           // not a local root
    int g = parent[t];
    if (g == t) return;         // already a global root, count in place
    while (true) { int pg = parent[g]; if (pg == g) break; g = pg; }
    parent[t] = g;
    atomicAdd(&counts[g], cnt);
    counts[t] = 0;
}

// per (img, class) max over roots of key = (count<<32) | ~root_index
#define BEST_BLK_PER_IMG 144
#define BEST_TPB 256
#define BEST_PIX_PER_BLK (HW / BEST_BLK_PER_IMG)  // 4096
__global__ void k_best(const uint8_t* __restrict__ labels,
                       const uint32_t* __restrict__ counts,
                       ull* __restrict__ best) {
    __shared__ ull sw[(BEST_TPB / 64) * 3];
    int img = blockIdx.x / BEST_BLK_PER_IMG;
    int chunk = blockIdx.x % BEST_BLK_PER_IMG;
    int base = img * HW + chunk * BEST_PIX_PER_BLK;

    ull l0 = 0, l1 = 0, l2 = 0;
    for (int k = 0; k < BEST_PIX_PER_BLK; k += BEST_TPB * 4) {
        int t = base + k + (int)threadIdx.x * 4;
        uint4 cv = *(const uint4*)&counts[t];
        if (cv.x | cv.y | cv.z | cv.w) {
            uchar4 lv = *(const uchar4*)&labels[t];
            uint32_t cs[4] = {cv.x, cv.y, cv.z, cv.w};
            uint8_t ls[4] = {lv.x, lv.y, lv.z, lv.w};
            #pragma unroll
            for (int j = 0; j < 4; ++j) {
                if (cs[j]) {
                    int c = (int)ls[j] - 1;
                    ull key = ((ull)cs[j] << 32) | (ull)(~(uint32_t)(t + j));
                    if (c == 0) l0 = umax64(l0, key);
                    else if (c == 1) l1 = umax64(l1, key);
                    else l2 = umax64(l2, key);
                }
            }
        }
    }
    #pragma unroll
    for (int m = 1; m < 64; m <<= 1) {
        l0 = umax64(l0, __shfl_xor(l0, m, 64));
        l1 = umax64(l1, __shfl_xor(l1, m, 64));
        l2 = umax64(l2, __shfl_xor(l2, m, 64));
    }
    int lane = threadIdx.x & 63;
    int wid = threadIdx.x >> 6;
    if (lane == 0) { sw[wid * 3 + 0] = l0; sw[wid * 3 + 1] = l1; sw[wid * 3 + 2] = l2; }
    __syncthreads();
    if (threadIdx.x < 3) {
        ull m = 0;
        for (int w = 0; w < BEST_TPB / 64; ++w) m = umax64(m, sw[w * 3 + threadIdx.x]);
        if (m) atomicMax(&best[(img * 3 + (int)threadIdx.x) * BEST_STRIDE], m);
    }
}

// final output: global root = parent[parent[t]] (local roots point at global roots)
__global__ void k_output(const uint8_t* __restrict__ labels,
                         const int* __restrict__ parent,
                         const ull* __restrict__ best,
                         float* __restrict__ out) {
    int q = blockIdx.x * blockDim.x + threadIdx.x;
    if (q >= NPIX / 4) return;
    int t = q * 4;
    int b = t / HW;
    int i = t - b * HW;
    uchar4 lv = *(const uchar4*)&labels[t];
    int4 pv = *(const int4*)&parent[t];
    int root[3];
    root[0] = (int)(~(uint32_t)best[(b * 3 + 0) * BEST_STRIDE]);
    root[1] = (int)(~(uint32_t)best[(b * 3 + 1) * BEST_STRIDE]);
    root[2] = (int)(~(uint32_t)best[(b * 3 + 2) * BEST_STRIDE]);

    uint8_t ls[4] = {lv.x, lv.y, lv.z, lv.w};
    int ps[4] = {pv.x, pv.y, pv.z, pv.w};
    float fg[4];
    #pragma unroll
    for (int j = 0; j < 4; ++j) {
        int g = -1;
        if (ps[j] >= 0) g = parent[ps[j]];  // tile-local -> cache hit
        fg[j] = (ls[j] && g == root[ls[j] - 1]) ? 1.0f : 0.0f;
    }

    float4 o0, o1, o2, o3;
    float* c0 = &o0.x; float* c1 = &o1.x; float* c2 = &o2.x; float* c3 = &o3.x;
    #pragma unroll
    for (int j = 0; j < 4; ++j) {
        c0[j] = 1.0f - fg[j];
        c1[j] = (ls[j] == 1) ? fg[j] : 0.0f;
        c2[j] = (ls[j] == 2) ? fg[j] : 0.0f;
        c3[j] = (ls[j] == 3) ? fg[j] : 0.0f;
    }
    float* o = out + (size_t)b * CC * HW + i;
    *(float4*)&o[0] = o0;
    *(float4*)&o[HW] = o1;
    *(float4*)&o[2 * HW] = o2;
    *(float4*)&o[3 * HW] = o3;
}

// ---------------- launch ----------------

extern "C" void kernel_launch(void* const* d_in, const int* in_sizes, int n_in,
                              void* d_out, int out_size, void* d_ws, size_t ws_size,
                              hipStream_t stream) {
    const float* pred = (const float*)d_in[0];
    float* out = (float*)d_out;

    uint8_t* labels = (uint8_t*)d_ws;                            // NPIX bytes
    int* parent = (int*)((char*)d_ws + NPIX);                    // NPIX*4 bytes
    ull* best = (ull*)((char*)d_ws + NPIX + (size_t)NPIX * 4);   // NIMG*BEST_STRIDE*8
    uint32_t* counts = (uint32_t*)d_out;  // reuse d_out; overwritten by k_output

    const int TPB = 256;

    k_tile_ccl<<<BB * TILES_PER_IMG, CCL_TPB, 0, stream>>>(pred, labels, parent, counts, best);
    k_border_merge<<<(BB * EDGES_PER_IMG + TPB - 1) / TPB, TPB, 0, stream>>>(labels, parent);
    k_compress<<<(NPIX + TPB - 1) / TPB, TPB, 0, stream>>>(parent, counts);
    k_best<<<BB * BEST_BLK_PER_IMG, BEST_TPB, 0, stream>>>(labels, counts, best);
    k_output<<<(NPIX / 4 + TPB - 1) / TPB, TPB, 0, stream>>>(labels, parent, best, out);
}

// Round 5
// 151.999 us; speedup vs baseline: 4.7654x; 1.2211x over previous
//
#include <hip/hip_runtime.h>
#include <stdint.h>

#define BB 16
#define CC 4
#define HH 768
#define WW 768
#define HW (HH * WW)          // 589824
#define NPIX (BB * HW)        // 9437184
#define NIMG (BB * (CC - 1))  // 48
#define BEST_STRIDE 16        // ull entries -> 128 B per (img,class)

#define TS 64                 // tile side
#define TPI (WW / TS)         // 12 tiles per image dim
#define TILES_PER_IMG (TPI * TPI)  // 144
#define TPIX (TS * TS)        // 4096
#define CCL_TPB 256

typedef unsigned long long ull;

// ---------------- global union-find (border merges only) ----------------

__device__ __forceinline__ int find_root(int* P, int i) {
    int p = P[i];
    while (p != i) {
        int gp = P[p];
        P[i] = gp;   // path halving (benign race)
        i = p;
        p = gp;
    }
    return i;
}

__device__ __forceinline__ void merge(int* P, int a, int b) {
    a = find_root(P, a);
    b = find_root(P, b);
    while (a != b) {
        if (a < b) { int t = a; a = b; b = t; }  // a = larger root
        int old = atomicCAS(&P[a], a, b);        // attach larger under smaller
        if (old == a) return;
        a = find_root(P, old);
        b = find_root(P, b);
    }
}

// ---------------- LDS union-find ----------------

__device__ __forceinline__ int lfind(int* P, int i) {
    int p = P[i];
    while (p != i) {
        int gp = P[p];
        P[i] = gp;
        i = p;
        p = gp;
    }
    return i;
}

__device__ __forceinline__ void lmerge(int* P, int a, int b) {
    a = lfind(P, a);
    b = lfind(P, b);
    while (a != b) {
        if (a < b) { int t = a; a = b; b = t; }
        int old = atomicCAS(&P[a], a, b);
        if (old == a) return;
        a = lfind(P, old);
        b = lfind(P, b);
    }
}

// find with count-bits masking: sp[root] may hold root | (count<<16).
// path-halving writes only to non-root entries (their high bits are 0).
__device__ __forceinline__ int lfind_masked(int* P, int i) {
    int p = P[i] & 0xFFFF;
    while (p != i) {
        int gp = P[p] & 0xFFFF;
        P[i] = gp;
        i = p;
        p = gp;
    }
    return i;
}

__device__ __forceinline__ ull umax64(ull a, ull b) { return a > b ? a : b; }

// ---------------- kernels ----------------

// per 64x64 tile: argmax -> labels; run-based local CCL in LDS; counts in sp high bits.
// writes: labels; parent[pix] = global idx of tile-local root (-1 bg);
//         counts[pix] = local component size at local-root pixels, 0 elsewhere.
__global__ __launch_bounds__(CCL_TPB) void k_tile_ccl(
        const float* __restrict__ pred,
        uint8_t* __restrict__ labels,
        int* __restrict__ parent,
        uint32_t* __restrict__ counts,
        ull* __restrict__ best) {
    __shared__ int sp[TPIX];         // 16 KB: parent; root entries gain count<<16 in 3a
    __shared__ uint8_t slab[TPIX];   // 4 KB: labels; reused as root-flag in 3a

    if (blockIdx.x == 0) {
        for (int i = threadIdx.x; i < NIMG * BEST_STRIDE; i += CCL_TPB) best[i] = 0ull;
    }

    const int tid = (int)threadIdx.x;
    const int img = blockIdx.x / TILES_PER_IMG;
    const int tile = blockIdx.x % TILES_PER_IMG;
    const int tr = (tile / TPI) * TS;
    const int tc = (tile % TPI) * TS;
    const float* pb = pred + (size_t)img * CC * HW;
    const int imgbase = img * HW;

    // phase 1: argmax, 4 px/thread
    for (int k = 0; k < TPIX; k += CCL_TPB * 4) {
        int li = k + tid * 4;
        int gi = (tr + (li >> 6)) * WW + tc + (li & 63);
        float4 v0 = *(const float4*)&pb[gi];
        float4 v1 = *(const float4*)&pb[gi + HW];
        float4 v2 = *(const float4*)&pb[gi + 2 * HW];
        float4 v3 = *(const float4*)&pb[gi + 3 * HW];
        const float* a0 = &v0.x; const float* a1 = &v1.x;
        const float* a2 = &v2.x; const float* a3 = &v3.x;
        uchar4 lout;
        uint8_t* lj = &lout.x;
        #pragma unroll
        for (int j = 0; j < 4; ++j) {
            int lab = 0;
            float bv = a0[j];
            if (a1[j] > bv) { bv = a1[j]; lab = 1; }
            if (a2[j] > bv) { bv = a2[j]; lab = 2; }
            if (a3[j] > bv) { bv = a3[j]; lab = 3; }
            lj[j] = (uint8_t)lab;
        }
        *(uchar4*)&slab[li] = lout;
        *(uchar4*)&labels[imgbase + gi] = lout;
    }
    __syncthreads();

    const int c = tid & 63;  // wave lane == column within row

    // phase 2a: horizontal runs via ballot; sp[pix] = run-start index (-1 bg)
    #pragma unroll 1
    for (int it = 0; it < TPIX / CCL_TPB; ++it) {
        int li = it * CCL_TPB + tid;
        int lab = slab[li];
        int labL = __shfl_up(lab, 1, 64);
        bool isStart = lab && (c == 0 || labL != lab);
        ull mask = __ballot(isStart);
        int v = -1;
        if (lab) {
            ull mle = mask & (~0ull >> (63 - c));
            v = (li & ~63) + (63 - __clzll(mle));
        }
        sp[li] = v;
    }
    __syncthreads();

    // phase 2b: vertical merges, one per run-contact segment (crack criterion)
    #pragma unroll 1
    for (int it = 0; it < TPIX / CCL_TPB; ++it) {
        int li = it * CCL_TPB + tid;
        int lab = slab[li];
        int labU = (li >= TS) ? (int)slab[li - TS] : 0;
        int labL = __shfl_up(lab, 1, 64);
        int labUL = __shfl_up(labU, 1, 64);
        if (lab && labU == lab) {
            if (c == 0 || !(labL == lab && labUL == lab))
                lmerge(sp, li, li - TS);
        }
    }
    __syncthreads();

    // phase 3a: flatten; count via atomicAdd(1<<16) at root; root flag -> slab;
    // store parent (global root index per pixel) directly
    #pragma unroll 1
    for (int it = 0; it < TPIX / CCL_TPB; ++it) {
        int li = it * CCL_TPB + tid;
        int gidx = imgbase + (tr + (li >> 6)) * WW + tc + (li & 63);
        int s0 = sp[li];
        int pv = -1;
        uint8_t flag = 0;
        if (s0 >= 0) {
            int root = lfind_masked(sp, li);
            atomicAdd((unsigned int*)&sp[root], 0x10000u);
            flag = (uint8_t)(root == li);
            pv = imgbase + (tr + (root >> 6)) * WW + tc + (root & 63);
        }
        slab[li] = flag;
        parent[gidx] = pv;
    }
    __syncthreads();

    // phase 3b: counts, 4 px/thread (count = sp high 16 bits at flagged roots)
    for (int k = 0; k < TPIX; k += CCL_TPB * 4) {
        int li = k + tid * 4;
        int gi = imgbase + (tr + (li >> 6)) * WW + tc + (li & 63);
        uchar4 fl = *(const uchar4*)&slab[li];
        int4 sv = *(const int4*)&sp[li];
        uint4 cout;
        cout.x = fl.x ? ((uint32_t)sv.x >> 16) : 0u;
        cout.y = fl.y ? ((uint32_t)sv.y >> 16) : 0u;
        cout.z = fl.z ? ((uint32_t)sv.z >> 16) : 0u;
        cout.w = fl.w ? ((uint32_t)sv.w >> 16) : 0u;
        *(uint4*)&counts[gi] = cout;
    }
}

// merge across tile borders only
#define VEDGES ((TPI - 1) * HH)             // 8448
#define EDGES_PER_IMG (2 * (TPI - 1) * HH)  // 16896
__global__ void k_border_merge(const uint8_t* __restrict__ labels, int* parent) {
    int t = blockIdx.x * blockDim.x + threadIdx.x;
    if (t >= BB * EDGES_PER_IMG) return;
    int img = t / EDGES_PER_IMG;
    int e = t % EDGES_PER_IMG;
    int a, b;
    if (e < VEDGES) {
        int j = e / HH, r = e % HH;
        int c = j * TS + TS - 1;
        a = r * WW + c;
        b = a + 1;
    } else {
        e -= VEDGES;
        int j = e / WW, c = e % WW;
        int r = j * TS + TS - 1;
        a = r * WW + c;
        b = a + WW;
    }
    int ga = img * HW + a, gb = img * HW + b;
    uint8_t la = labels[ga];
    if (la && labels[gb] == la) merge(parent, ga, gb);
}

// for each local root (counts>0): chase to global root, point parent directly at it,
// move its local count there (atomics only for merged roots)
__global__ void k_compress(int* __restrict__ parent, uint32_t* __restrict__ counts) {
    int t = blockIdx.x * blockDim.x + threadIdx.x;
    if (t >= NPIX) return;
    uint32_t cnt = counts[t];
    if (!cnt) return;           // not a local root
    int g = parent[t];
    if (g == t) return;         // already a global root
    while (true) { int pg = parent[g]; if (pg == g) break; g = pg; }
    parent[t] = g;
    atomicAdd(&counts[g], cnt);
    counts[t] = 0;
}

// per (img, class) max over roots of key = (count<<32) | ~root_index
#define BEST_BLK_PER_IMG 144
#define BEST_TPB 256
#define BEST_PIX_PER_BLK (HW / BEST_BLK_PER_IMG)  // 4096
__global__ void k_best(const uint8_t* __restrict__ labels,
                       const uint32_t* __restrict__ counts,
                       ull* __restrict__ best) {
    __shared__ ull sw[(BEST_TPB / 64) * 3];
    int img = blockIdx.x / BEST_BLK_PER_IMG;
    int chunk = blockIdx.x % BEST_BLK_PER_IMG;
    int base = img * HW + chunk * BEST_PIX_PER_BLK;

    ull l0 = 0, l1 = 0, l2 = 0;
    for (int k = 0; k < BEST_PIX_PER_BLK; k += BEST_TPB * 4) {
        int t = base + k + (int)threadIdx.x * 4;
        uint4 cv = *(const uint4*)&counts[t];
        if (cv.x | cv.y | cv.z | cv.w) {
            uchar4 lv = *(const uchar4*)&labels[t];
            uint32_t cs[4] = {cv.x, cv.y, cv.z, cv.w};
            uint8_t ls[4] = {lv.x, lv.y, lv.z, lv.w};
            #pragma unroll
            for (int j = 0; j < 4; ++j) {
                if (cs[j]) {
                    int cc = (int)ls[j] - 1;
                    ull key = ((ull)cs[j] << 32) | (ull)(~(uint32_t)(t + j));
                    if (cc == 0) l0 = umax64(l0, key);
                    else if (cc == 1) l1 = umax64(l1, key);
                    else l2 = umax64(l2, key);
                }
            }
        }
    }
    #pragma unroll
    for (int m = 1; m < 64; m <<= 1) {
        l0 = umax64(l0, __shfl_xor(l0, m, 64));
        l1 = umax64(l1, __shfl_xor(l1, m, 64));
        l2 = umax64(l2, __shfl_xor(l2, m, 64));
    }
    int lane = threadIdx.x & 63;
    int wid = threadIdx.x >> 6;
    if (lane == 0) { sw[wid * 3 + 0] = l0; sw[wid * 3 + 1] = l1; sw[wid * 3 + 2] = l2; }
    __syncthreads();
    if (threadIdx.x < 3) {
        ull m = 0;
        for (int w = 0; w < BEST_TPB / 64; ++w) m = umax64(m, sw[w * 3 + threadIdx.x]);
        if (m) atomicMax(&best[(img * 3 + (int)threadIdx.x) * BEST_STRIDE], m);
    }
}

// final output: global root = parent[parent[t]] (local roots point at global roots)
__global__ void k_output(const uint8_t* __restrict__ labels,
                         const int* __restrict__ parent,
                         const ull* __restrict__ best,
                         float* __restrict__ out) {
    int q = blockIdx.x * blockDim.x + threadIdx.x;
    if (q >= NPIX / 4) return;
    int t = q * 4;
    int b = t / HW;
    int i = t - b * HW;
    uchar4 lv = *(const uchar4*)&labels[t];
    int4 pv = *(const int4*)&parent[t];
    int root[3];
    root[0] = (int)(~(uint32_t)best[(b * 3 + 0) * BEST_STRIDE]);
    root[1] = (int)(~(uint32_t)best[(b * 3 + 1) * BEST_STRIDE]);
    root[2] = (int)(~(uint32_t)best[(b * 3 + 2) * BEST_STRIDE]);

    uint8_t ls[4] = {lv.x, lv.y, lv.z, lv.w};
    int ps[4] = {pv.x, pv.y, pv.z, pv.w};
    float fg[4];
    #pragma unroll
    for (int j = 0; j < 4; ++j) {
        int g = -1;
        if (ps[j] >= 0) g = parent[ps[j]];  // tile-local -> cache hit
        fg[j] = (ls[j] && g == root[ls[j] - 1]) ? 1.0f : 0.0f;
    }

    float4 o0, o1, o2, o3;
    float* c0 = &o0.x; float* c1 = &o1.x; float* c2 = &o2.x; float* c3 = &o3.x;
    #pragma unroll
    for (int j = 0; j < 4; ++j) {
        c0[j] = 1.0f - fg[j];
        c1[j] = (ls[j] == 1) ? fg[j] : 0.0f;
        c2[j] = (ls[j] == 2) ? fg[j] : 0.0f;
        c3[j] = (ls[j] == 3) ? fg[j] : 0.0f;
    }
    float* o = out + (size_t)b * CC * HW + i;
    *(float4*)&o[0] = o0;
    *(float4*)&o[HW] = o1;
    *(float4*)&o[2 * HW] = o2;
    *(float4*)&o[3 * HW] = o3;
}

// ---------------- launch ----------------

extern "C" void kernel_launch(void* const* d_in, const int* in_sizes, int n_in,
                              void* d_out, int out_size, void* d_ws, size_t ws_size,
                              hipStream_t stream) {
    const float* pred = (const float*)d_in[0];
    float* out = (float*)d_out;

    uint8_t* labels = (uint8_t*)d_ws;                            // NPIX bytes
    int* parent = (int*)((char*)d_ws + NPIX);                    // NPIX*4 bytes
    ull* best = (ull*)((char*)d_ws + NPIX + (size_t)NPIX * 4);   // NIMG*BEST_STRIDE*8
    uint32_t* counts = (uint32_t*)d_out;  // reuse d_out; overwritten by k_output

    const int TPB = 256;

    k_tile_ccl<<<BB * TILES_PER_IMG, CCL_TPB, 0, stream>>>(pred, labels, parent, counts, best);
    k_border_merge<<<(BB * EDGES_PER_IMG + TPB - 1) / TPB, TPB, 0, stream>>>(labels, parent);
    k_compress<<<(NPIX + TPB - 1) / TPB, TPB, 0, stream>>>(parent, counts);
    k_best<<<BB * BEST_BLK_PER_IMG, BEST_TPB, 0, stream>>>(labels, counts, best);
    k_output<<<(NPIX / 4 + TPB - 1) / TPB, TPB, 0, stream>>>(labels, parent, best, out);
}